// Round 7
// baseline (145.781 us; speedup 1.0000x reference)
//
#include <hip/hip_runtime.h>
#include <hip/hip_bf16.h>

typedef __attribute__((ext_vector_type(8))) short bf16x8;
typedef __attribute__((ext_vector_type(4))) short bf16x4;
typedef __attribute__((ext_vector_type(16))) float f32x16;
typedef unsigned short u16;
typedef unsigned int u32;

#define S_LEN 2048
#define HD 64

__device__ __forceinline__ u16 f2bf(float x) {
  __hip_bfloat16 h = __float2bfloat16(x);
  return __builtin_bit_cast(u16, h);
}

// pack 2 f32 -> 2 bf16 in one instr (src0 -> lo16, src1 -> hi16)
__device__ __forceinline__ u32 cvtpk(float lo, float hi) {
  u32 r;
  asm("v_cvt_pk_bf16_f32 %0, %1, %2" : "=v"(r) : "v"(lo), "v"(hi));
  return r;
}

// ushort-index swizzle for tiles with 64-ushort (128B) rows: byte ^= ((row&7)<<4)
__device__ __forceinline__ int swz(int idx) {
  return idx ^ (((idx >> 6) & 7) << 3);
}

__device__ __forceinline__ void gload16(const u16* g, u16* lds) {
  __builtin_amdgcn_global_load_lds(
      (const __attribute__((address_space(1))) u32*)g,
      (__attribute__((address_space(3))) u32*)lds, 16, 0, 0);
}

#if __has_builtin(__builtin_amdgcn_mfma_f32_32x32x8bf16_1k)
__device__ __forceinline__ f32x16 mfma8(bf16x4 a, bf16x4 b, f32x16 c) {
  return __builtin_amdgcn_mfma_f32_32x32x8bf16_1k(a, b, c, 0, 0, 0);
}
#else
__device__ __forceinline__ f32x16 mfma8(bf16x4 a, bf16x4 b, f32x16 c) {
  asm volatile("v_mfma_f32_32x32x8_bf16 %0, %1, %2, %0\n\ts_nop 7\n\ts_nop 7"
               : "+v"(c) : "v"(a), "v"(b));
  return c;
}
#endif

// Fused prep: K -> bf16; V -> bf16 transposed VT[b][d][kv'] with kv granule
// permutation (within each 16: granule order 0,2,1,3 — involution) so PV can
// read one b128 that feeds two x8-MFMA k-granules directly.
__global__ void prep(const float* __restrict__ K, const float* __restrict__ V,
                     u16* __restrict__ Kb, u16* __restrict__ VTb) {
  int i = blockIdx.x * 256 + threadIdx.x;
  if (i < 65536) {
    float4 v = reinterpret_cast<const float4*>(K)[i];
    ushort4 o;
    o.x = f2bf(v.x); o.y = f2bf(v.y); o.z = f2bf(v.z); o.w = f2bf(v.w);
    reinterpret_cast<ushort4*>(Kb)[i] = o;
  } else {
    int j = i - 65536;
    int kv2 = j & (S_LEN - 1);
    int r = j >> 11;
    int d = r & 63;
    int b = r >> 6;
    int g = (kv2 >> 2) & 3;
    int gs = ((g & 1) << 1) | (g >> 1);          // swap granules 1<->2
    int kvs = (kv2 & ~15) | (gs << 2) | (kv2 & 3);
    VTb[j] = f2bf(V[((size_t)(b * S_LEN + kvs)) * HD + d]);
  }
}

// Swapped-QK^T flash attention, P fully in-lane.
// QK^T: mfma_f32_32x32x16_bf16 seeded with C = -m (folds the softmax subtract).
// S^T acc: col=q(lane&31), kv=(r&3)+8(r>>2)+4hi.
// PV: mfma_f32_32x32x8_bf16, A-layout == S^T acc layout (no cross-lane moves).
__launch_bounds__(256, 2)
__global__ void attn_fwd(const float* __restrict__ Q, const u16* __restrict__ Kb,
                         const u16* __restrict__ VTb, float* __restrict__ out) {
  __shared__ u16 Kt[2][64 * 64];    // [kv][d] 8KB x2
  __shared__ u16 VTt[2][64 * 64];   // [d][kv'] 8KB x2

  const int tid = threadIdx.x;
  const int w = tid >> 6;
  const int lane = tid & 63;
  const int q = lane & 31;
  const int hi = lane >> 5;

  const int bh = blockIdx.x >> 4;
  const int qt = blockIdx.x & 15;
  const int b = bh >> 4;
  const int q0w = qt * 128 + w * 32;

  const u16* Kbase = Kb + (size_t)b * S_LEN * HD;
  const u16* Vbase = VTb + (size_t)b * HD * S_LEN;

  const int sr = lane >> 3;
  const int cs = (lane & 7) ^ sr;       // pre-swizzled 16B chunk

  // ---- Q fragments (B-operand): lane holds Q[q0w+q][16s+8hi+j], scaled
  const float qs = 0.125f * 1.44269504f;   // 1/sqrt(64) * log2(e)
  bf16x8 qreg[4];
  {
    const float* qrow = Q + ((size_t)(bh * S_LEN + q0w + q)) * HD + 8 * hi;
    #pragma unroll
    for (int s = 0; s < 4; ++s) {
      float4 f0 = *reinterpret_cast<const float4*>(qrow + 16 * s);
      float4 f1 = *reinterpret_cast<const float4*>(qrow + 16 * s + 4);
      bf16x8 v;
      v[0] = f2bf(f0.x * qs); v[1] = f2bf(f0.y * qs);
      v[2] = f2bf(f0.z * qs); v[3] = f2bf(f0.w * qs);
      v[4] = f2bf(f1.x * qs); v[5] = f2bf(f1.y * qs);
      v[6] = f2bf(f1.z * qs); v[7] = f2bf(f1.w * qs);
      qreg[s] = v;
    }
  }

  f32x16 oacc0, oacc1, minit;
  #pragma unroll
  for (int i = 0; i < 16; ++i) { oacc0[i] = 0.f; oacc1[i] = 0.f; minit[i] = 0.f; }
  float m = 0.f, l = 0.f;    // m0 = 0: defer-max keeps p <= 2^8 (T13)

  // ---- prologue: stage tile 0 into buf 0
  #pragma unroll
  for (int h = 0; h < 2; ++h) {
    int row = h * 32 + w * 8 + sr;
    gload16(Kbase + (size_t)row * HD + cs * 8, &Kt[0][h * 2048 + w * 512]);
    gload16(Vbase + (size_t)row * S_LEN + cs * 8, &VTt[0][h * 2048 + w * 512]);
  }
  __syncthreads();

  int cur = 0;
  for (int t = 0; t < 32; ++t) {
    if (t != 31) {
      int kv1 = (t + 1) * 64;
      #pragma unroll
      for (int h = 0; h < 2; ++h) {
        int row = h * 32 + w * 8 + sr;
        gload16(Kbase + (size_t)(kv1 + row) * HD + cs * 8,
                &Kt[cur ^ 1][h * 2048 + w * 512]);
        gload16(Vbase + (size_t)row * S_LEN + kv1 + cs * 8,
                &VTt[cur ^ 1][h * 2048 + w * 512]);
      }
    }

    // ---- S^T - m = K Q^T + (-m)  (C-operand seeds the softmax subtract)
    __builtin_amdgcn_s_setprio(1);
    bf16x8 ka0 = *reinterpret_cast<const bf16x8*>(&Kt[cur][swz(q * 64 + 8 * hi)]);
    bf16x8 ka1 = *reinterpret_cast<const bf16x8*>(&Kt[cur][swz((32 + q) * 64 + 8 * hi)]);
    f32x16 s0 = __builtin_amdgcn_mfma_f32_32x32x16_bf16(ka0, qreg[0], minit, 0, 0, 0);
    f32x16 s1 = __builtin_amdgcn_mfma_f32_32x32x16_bf16(ka1, qreg[0], minit, 0, 0, 0);
    #pragma unroll
    for (int s = 1; s < 4; ++s) {
      bf16x8 k0 = *reinterpret_cast<const bf16x8*>(&Kt[cur][swz(q * 64 + 16 * s + 8 * hi)]);
      bf16x8 k1 = *reinterpret_cast<const bf16x8*>(&Kt[cur][swz((32 + q) * 64 + 16 * s + 8 * hi)]);
      s0 = __builtin_amdgcn_mfma_f32_32x32x16_bf16(k0, qreg[s], s0, 0, 0, 0);
      s1 = __builtin_amdgcn_mfma_f32_32x32x16_bf16(k1, qreg[s], s1, 0, 0, 0);
    }
    __builtin_amdgcn_s_setprio(0);

    // ---- tile max (relative to m), 4-way ILP tree + one cross-half shfl
    float ma = s0[0], mb = s0[1], mc = s0[2], md = s0[3];
    #pragma unroll
    for (int i = 4; i < 16; i += 4) {
      ma = fmaxf(ma, s0[i]);     mb = fmaxf(mb, s0[i + 1]);
      mc = fmaxf(mc, s0[i + 2]); md = fmaxf(md, s0[i + 3]);
    }
    #pragma unroll
    for (int i = 0; i < 16; i += 4) {
      ma = fmaxf(ma, s1[i]);     mb = fmaxf(mb, s1[i + 1]);
      mc = fmaxf(mc, s1[i + 2]); md = fmaxf(md, s1[i + 3]);
    }
    float pm = fmaxf(fmaxf(ma, mb), fmaxf(mc, md));
    pm = fmaxf(pm, __shfl_xor(pm, 32));

    // ---- P = exp2(S - m); defer-max slow path only when max grew by > 8
    float p0v[16], p1v[16];
    if (__builtin_expect(__any(pm > 8.f), 0)) {
      float delta = fmaxf(pm, 0.f);
      float corr = exp2f(-delta);
      m += delta;
      l *= corr;
      #pragma unroll
      for (int i = 0; i < 16; ++i) minit[i] = -m;
      #pragma unroll
      for (int r = 0; r < 16; ++r) {
        int qr = (r & 3) + 8 * (r >> 2) + 4 * hi;
        float cr = __shfl(corr, qr);
        oacc0[r] *= cr;
        oacc1[r] *= cr;
      }
      #pragma unroll
      for (int i = 0; i < 16; ++i) p0v[i] = exp2f(s0[i] - delta);
      #pragma unroll
      for (int i = 0; i < 16; ++i) p1v[i] = exp2f(s1[i] - delta);
    } else {
      #pragma unroll
      for (int i = 0; i < 16; ++i) p0v[i] = exp2f(s0[i]);
      #pragma unroll
      for (int i = 0; i < 16; ++i) p1v[i] = exp2f(s1[i]);
    }

    // ---- row-sum partials (4-way tree)
    {
      float sa_ = p0v[0], sb_ = p0v[1], sc_ = p0v[2], sd_ = p0v[3];
      #pragma unroll
      for (int i = 4; i < 16; i += 4) {
        sa_ += p0v[i];     sb_ += p0v[i + 1];
        sc_ += p0v[i + 2]; sd_ += p0v[i + 3];
      }
      #pragma unroll
      for (int i = 0; i < 16; i += 4) {
        sa_ += p1v[i];     sb_ += p1v[i + 1];
        sc_ += p1v[i + 2]; sd_ += p1v[i + 3];
      }
      l += (sa_ + sb_) + (sc_ + sd_);
    }

    // ---- pack P to bf16 words (single-instr cvt_pk)
    u32 pw[16];
    #pragma unroll
    for (int k = 0; k < 8; ++k) pw[k] = cvtpk(p0v[2 * k], p0v[2 * k + 1]);
    #pragma unroll
    for (int k = 0; k < 8; ++k) pw[8 + k] = cvtpk(p1v[2 * k], p1v[2 * k + 1]);

    // ---- O += P V : b128 V reads feed two x8 granules each (perm'd layout)
    union PW2 { u32 w[2]; bf16x4 v; };
    __builtin_amdgcn_s_setprio(1);
    #pragma unroll
    for (int tp = 0; tp < 4; ++tp) {
      bf16x8 vv0 = *reinterpret_cast<const bf16x8*>(&VTt[cur][swz(q * 64 + 16 * tp + 8 * hi)]);
      bf16x8 vv1 = *reinterpret_cast<const bf16x8*>(&VTt[cur][swz((32 + q) * 64 + 16 * tp + 8 * hi)]);
      bf16x4 vl0 = __builtin_shufflevector(vv0, vv0, 0, 1, 2, 3);
      bf16x4 vh0 = __builtin_shufflevector(vv0, vv0, 4, 5, 6, 7);
      bf16x4 vl1 = __builtin_shufflevector(vv1, vv1, 0, 1, 2, 3);
      bf16x4 vh1 = __builtin_shufflevector(vv1, vv1, 4, 5, 6, 7);
      PW2 pa, pb;
      pa.w[0] = pw[4 * tp + 0]; pa.w[1] = pw[4 * tp + 1];
      pb.w[0] = pw[4 * tp + 2]; pb.w[1] = pw[4 * tp + 3];
      oacc0 = mfma8(pa.v, vl0, oacc0);
      oacc0 = mfma8(pb.v, vh0, oacc0);
      oacc1 = mfma8(pa.v, vl1, oacc1);
      oacc1 = mfma8(pb.v, vh1, oacc1);
    }
    __builtin_amdgcn_s_setprio(0);

    __syncthreads();
    cur ^= 1;
  }

  // ---- epilogue
  float lt = l + __shfl_xor(l, 32);
  float invq = 1.0f / lt;
  #pragma unroll
  for (int r = 0; r < 16; ++r) {
    int qr = (r & 3) + 8 * (r >> 2) + 4 * hi;
    float iv = __shfl(invq, qr);
    size_t o = ((size_t)(bh * S_LEN + q0w + qr)) * HD + q;
    out[o] = oacc0[r] * iv;
    out[o + 32] = oacc1[r] * iv;
  }
}

extern "C" void kernel_launch(void* const* d_in, const int* in_sizes, int n_in,
                              void* d_out, int out_size, void* d_ws, size_t ws_size,
                              hipStream_t stream) {
  const float* Q = (const float*)d_in[0];
  const float* K = (const float*)d_in[1];
  const float* V = (const float*)d_in[2];
  float* out = (float*)d_out;

  const int KN = 2 * S_LEN * HD;
  u16* Kb = (u16*)d_ws;
  u16* VTb = Kb + KN;

  hipLaunchKernelGGL(prep, dim3((65536 + KN) / 256), dim3(256), 0, stream,
                     K, V, Kb, VTb);
  hipLaunchKernelGGL(attn_fwd, dim3(512), dim3(256), 0, stream, Q, Kb, VTb, out);
}

// Round 9
// 127.032 us; speedup vs baseline: 1.1476x; 1.1476x over previous
//
#include <hip/hip_runtime.h>
#include <hip/hip_bf16.h>

typedef __attribute__((ext_vector_type(8))) short bf16x8;
typedef __attribute__((ext_vector_type(4))) short bf16x4;
typedef __attribute__((ext_vector_type(16))) float f32x16;
typedef unsigned short u16;
typedef unsigned int u32;

#define S_LEN 2048
#define HD 64

#if __has_builtin(__builtin_amdgcn_exp2f)
#define EXP2(x) __builtin_amdgcn_exp2f(x)
#else
#define EXP2(x) exp2f(x)
#endif

__device__ __forceinline__ u16 f2bf(float x) {
  __hip_bfloat16 h = __float2bfloat16(x);
  return __builtin_bit_cast(u16, h);
}

// pack two floats to bf16 pair; compiler fuses to v_cvt_pk (m240: don't hand-asm)
__device__ __forceinline__ u32 pk2(float lo, float hi) {
  return ((u32)f2bf(hi) << 16) | (u32)f2bf(lo);
}

// ushort-index swizzle for tiles with 64-ushort (128B) rows: byte ^= ((row&7)<<4)
__device__ __forceinline__ int swz(int idx) {
  return idx ^ (((idx >> 6) & 7) << 3);
}

__device__ __forceinline__ void gload16(const u16* g, u16* lds) {
  __builtin_amdgcn_global_load_lds(
      (const __attribute__((address_space(1))) u32*)g,
      (__attribute__((address_space(3))) u32*)lds, 16, 0, 0);
}

#if __has_builtin(__builtin_amdgcn_mfma_f32_32x32x8bf16_1k)
__device__ __forceinline__ f32x16 mfma8(bf16x4 a, bf16x4 b, f32x16 c) {
  return __builtin_amdgcn_mfma_f32_32x32x8bf16_1k(a, b, c, 0, 0, 0);
}
#else
__device__ __forceinline__ f32x16 mfma8(bf16x4 a, bf16x4 b, f32x16 c) {
  asm volatile("v_mfma_f32_32x32x8_bf16 %0, %1, %2, %0\n\ts_nop 7\n\ts_nop 7"
               : "+v"(c) : "v"(a), "v"(b));
  return c;
}
#endif

// Fused prep: K -> bf16; V -> bf16 transposed VT[b][d][kv'] with kv granule
// permutation (within each 16: granule order 0,2,1,3 — involution) so PV can
// read one b128 that feeds two x8-MFMA k-granules directly.
__global__ void prep(const float* __restrict__ K, const float* __restrict__ V,
                     u16* __restrict__ Kb, u16* __restrict__ VTb) {
  int i = blockIdx.x * 256 + threadIdx.x;
  if (i < 65536) {
    float4 v = reinterpret_cast<const float4*>(K)[i];
    ushort4 o;
    o.x = f2bf(v.x); o.y = f2bf(v.y); o.z = f2bf(v.z); o.w = f2bf(v.w);
    reinterpret_cast<ushort4*>(Kb)[i] = o;
  } else {
    int j = i - 65536;
    int kv2 = j & (S_LEN - 1);
    int r = j >> 11;
    int d = r & 63;
    int b = r >> 6;
    int g = (kv2 >> 2) & 3;
    int gs = ((g & 1) << 1) | (g >> 1);          // swap granules 1<->2
    int kvs = (kv2 & ~15) | (gs << 2) | (kv2 & 3);
    VTb[j] = f2bf(V[((size_t)(b * S_LEN + kvs)) * HD + d]);
  }
}

// Swapped-QK^T flash attention; in-block KV-split (2 wave-groups of 4), merged
// in LDS at block end. Per wave: 32 q-rows x 1024 kv.
// S^T acc: col=q(lane&31), kv=(r&3)+8(r>>2)+4hi. PV A-layout == S^T acc layout.
__launch_bounds__(512, 4)
__global__ void attn_fwd(const float* __restrict__ Q, const u16* __restrict__ Kb,
                         const u16* __restrict__ VTb, float* __restrict__ out) {
  // [buf][half]: K tile at +0, VT tile at +4096 (u16 units). 64 KB total.
  __shared__ __align__(16) u16 smem[32768];

  const int tid = threadIdx.x;
  const int w = tid >> 6;            // 0..7
  const int wq = w & 3;              // pair id (shares q-rows)
  const int half = w >> 2;           // kv half
  const int lane = tid & 63;
  const int q = lane & 31;
  const int hi = lane >> 5;

  const int bh = blockIdx.x >> 4;
  const int qt = blockIdx.x & 15;
  const int b = bh >> 4;
  const int q0w = qt * 128 + wq * 32;

  const u16* Kbase = Kb + (size_t)b * S_LEN * HD;
  const u16* Vbase = VTb + (size_t)b * HD * S_LEN;

  const int sr = lane >> 3;
  const int cs = (lane & 7) ^ sr;    // pre-swizzled 16B chunk

  // ---- Q fragments (B-operand): lane holds Q[q0w+q][16s+8hi+j], scaled
  const float qs = 0.125f * 1.44269504f;   // 1/sqrt(64) * log2(e)
  bf16x8 qreg[4];
  {
    const float* qrow = Q + ((size_t)(bh * S_LEN + q0w + q)) * HD + 8 * hi;
    #pragma unroll
    for (int s = 0; s < 4; ++s) {
      float4 f0 = *reinterpret_cast<const float4*>(qrow + 16 * s);
      float4 f1 = *reinterpret_cast<const float4*>(qrow + 16 * s + 4);
      bf16x8 v;
      v[0] = f2bf(f0.x * qs); v[1] = f2bf(f0.y * qs);
      v[2] = f2bf(f0.z * qs); v[3] = f2bf(f0.w * qs);
      v[4] = f2bf(f1.x * qs); v[5] = f2bf(f1.y * qs);
      v[6] = f2bf(f1.z * qs); v[7] = f2bf(f1.w * qs);
      qreg[s] = v;
    }
  }

  f32x16 oacc0, oacc1;
  #pragma unroll
  for (int i = 0; i < 16; ++i) { oacc0[i] = 0.f; oacc1[i] = 0.f; }
  float m = 0.f, l = 0.f;   // m0=0: defer-max keeps p <= 2^8 (T13)

  // ---- prologue: stage this group's tile 0 into buf 0
  {
    int kv0 = half * 1024;
    u16* T = &smem[half * 8192];
    #pragma unroll
    for (int hh = 0; hh < 2; ++hh) {
      int r0 = wq * 16 + hh * 8;
      int row = r0 + sr;
      gload16(Kbase + (size_t)(kv0 + row) * HD + cs * 8, T + r0 * 64);
      gload16(Vbase + (size_t)row * S_LEN + kv0 + cs * 8, T + 4096 + r0 * 64);
    }
  }
  __syncthreads();

  int cur = 0;
  for (int t = 0; t < 16; ++t) {
    // ---- issue next tile's stage first (flies during compute)
    if (t != 15) {
      int kv1 = (half * 16 + t + 1) * 64;
      u16* T = &smem[((cur ^ 1) * 2 + half) * 8192];
      #pragma unroll
      for (int hh = 0; hh < 2; ++hh) {
        int r0 = wq * 16 + hh * 8;
        int row = r0 + sr;
        gload16(Kbase + (size_t)(kv1 + row) * HD + cs * 8, T + r0 * 64);
        gload16(Vbase + (size_t)row * S_LEN + kv1 + cs * 8, T + 4096 + r0 * 64);
      }
    }

    const u16* Kt = &smem[(cur * 2 + half) * 8192];
    const u16* VTt = Kt + 4096;

    // ---- S^T = K Q^T (log2 units)
    f32x16 s0, s1;
    #pragma unroll
    for (int i = 0; i < 16; ++i) { s0[i] = 0.f; s1[i] = 0.f; }
    __builtin_amdgcn_s_setprio(1);
    #pragma unroll
    for (int s = 0; s < 4; ++s) {
      bf16x8 k0 = *reinterpret_cast<const bf16x8*>(&Kt[swz(q * 64 + 16 * s + 8 * hi)]);
      bf16x8 k1 = *reinterpret_cast<const bf16x8*>(&Kt[swz((32 + q) * 64 + 16 * s + 8 * hi)]);
      s0 = __builtin_amdgcn_mfma_f32_32x32x16_bf16(k0, qreg[s], s0, 0, 0, 0);
      s1 = __builtin_amdgcn_mfma_f32_32x32x16_bf16(k1, qreg[s], s1, 0, 0, 0);
    }
    __builtin_amdgcn_s_setprio(0);

    // ---- tile max + one cross-half shfl
    float pm = s0[0];
    #pragma unroll
    for (int i = 1; i < 16; ++i) pm = fmaxf(pm, s0[i]);
    #pragma unroll
    for (int i = 0; i < 16; ++i) pm = fmaxf(pm, s1[i]);
    pm = fmaxf(pm, __shfl_xor(pm, 32));

    // T13 defer-max: rescale only when max grew by > 8 (log2)
    if (__any(pm > m + 8.f)) {
      float mn = fmaxf(m, pm);
      float corr = EXP2(m - mn);
      m = mn;
      l *= corr;
      #pragma unroll
      for (int r = 0; r < 16; ++r) {
        int qr = (r & 3) + 8 * (r >> 2) + 4 * hi;
        float cr = __shfl(corr, qr);
        oacc0[r] *= cr;
        oacc1[r] *= cr;
      }
    }

    // ---- P = exp2(S - m); partial row-sum
    float p0v[16], p1v[16];
    float la = 0.f;
    #pragma unroll
    for (int i = 0; i < 16; ++i) { p0v[i] = EXP2(s0[i] - m); la += p0v[i]; }
    #pragma unroll
    for (int i = 0; i < 16; ++i) { p1v[i] = EXP2(s1[i] - m); la += p1v[i]; }
    l += la;

    // ---- pack P to bf16 words
    u32 pw[16];
    #pragma unroll
    for (int k = 0; k < 8; ++k) pw[k] = pk2(p0v[2 * k], p0v[2 * k + 1]);
    #pragma unroll
    for (int k = 0; k < 8; ++k) pw[8 + k] = pk2(p1v[2 * k], p1v[2 * k + 1]);

    // ---- O += P V : b128 V reads feed two x8 granules each (perm'd layout)
    union PW2 { u32 w[2]; bf16x4 v; };
    __builtin_amdgcn_s_setprio(1);
    #pragma unroll
    for (int tp = 0; tp < 4; ++tp) {
      bf16x8 vv0 = *reinterpret_cast<const bf16x8*>(&VTt[swz(q * 64 + 16 * tp + 8 * hi)]);
      bf16x8 vv1 = *reinterpret_cast<const bf16x8*>(&VTt[swz((32 + q) * 64 + 16 * tp + 8 * hi)]);
      bf16x4 vl0 = __builtin_shufflevector(vv0, vv0, 0, 1, 2, 3);
      bf16x4 vh0 = __builtin_shufflevector(vv0, vv0, 4, 5, 6, 7);
      bf16x4 vl1 = __builtin_shufflevector(vv1, vv1, 0, 1, 2, 3);
      bf16x4 vh1 = __builtin_shufflevector(vv1, vv1, 4, 5, 6, 7);
      PW2 pa, pb;
      pa.w[0] = pw[4 * tp + 0]; pa.w[1] = pw[4 * tp + 1];
      pb.w[0] = pw[4 * tp + 2]; pb.w[1] = pw[4 * tp + 3];
      oacc0 = mfma8(pa.v, vl0, oacc0);
      oacc0 = mfma8(pb.v, vh0, oacc0);
      oacc1 = mfma8(pa.v, vl1, oacc1);
      oacc1 = mfma8(pb.v, vh1, oacc1);
    }
    __builtin_amdgcn_s_setprio(0);

    __syncthreads();    // drains vmcnt: next tile staged
    cur ^= 1;
  }

  // ---- merge the two kv halves in LDS, then store (group 0 does the store)
  float lt = l + __shfl_xor(l, 32);    // full half-range row-sum, per q
  float* fO = (float*)smem;            // [4 pairs][32 rows][64 lanes] = 32 KB
  float* fL = fO + 8192;               // [4][32]
  float* fM = fL + 128;                // [4][32]

  if (half == 1) {
    #pragma unroll
    for (int r = 0; r < 16; ++r) {
      fO[(wq * 32 + r) * 64 + lane] = oacc0[r];
      fO[(wq * 32 + 16 + r) * 64 + lane] = oacc1[r];
    }
    if (hi == 0) { fL[wq * 32 + q] = lt; fM[wq * 32 + q] = m; }
  }
  __syncthreads();
  if (half == 0) {
    #pragma unroll
    for (int r = 0; r < 16; ++r) {
      int qr = (r & 3) + 8 * (r >> 2) + 4 * hi;
      float mA = __shfl(m, qr);
      float lA = __shfl(lt, qr);
      float mB = fM[wq * 32 + qr];
      float lB = fL[wq * 32 + qr];
      float M = fmaxf(mA, mB);
      float ca = EXP2(mA - M), cb = EXP2(mB - M);
      float iv = 1.0f / (ca * lA + cb * lB);
      float ob0 = fO[(wq * 32 + r) * 64 + lane];
      float ob1 = fO[(wq * 32 + 16 + r) * 64 + lane];
      size_t o = ((size_t)(bh * S_LEN + q0w + qr)) * HD + q;
      out[o]      = (ca * oacc0[r] + cb * ob0) * iv;
      out[o + 32] = (ca * oacc1[r] + cb * ob1) * iv;
    }
  }
}

extern "C" void kernel_launch(void* const* d_in, const int* in_sizes, int n_in,
                              void* d_out, int out_size, void* d_ws, size_t ws_size,
                              hipStream_t stream) {
  const float* Q = (const float*)d_in[0];
  const float* K = (const float*)d_in[1];
  const float* V = (const float*)d_in[2];
  float* out = (float*)d_out;

  const int KN = 2 * S_LEN * HD;
  u16* Kb = (u16*)d_ws;
  u16* VTb = Kb + KN;

  hipLaunchKernelGGL(prep, dim3((65536 + KN) / 256), dim3(256), 0, stream,
                     K, V, Kb, VTb);
  // 32 bh pairs x 16 q-tiles of 128 rows; 8 waves: 4 q-pairs x 2 kv halves
  hipLaunchKernelGGL(attn_fwd, dim3(512), dim3(512), 0, stream, Q, Kb, VTb, out);
}